// Round 1
// baseline (384.919 us; speedup 1.0000x reference)
//
#include <hip/hip_runtime.h>
#include <hip/hip_bf16.h>

#define T_TOK 4096
#define HDIM 1024
#define IDIM 1024
#define EDIM 8
#define HID_SHARED_BASE 8320   // routed hid rows [0,8320); shared at [8320,12416)

typedef __attribute__((ext_vector_type(8))) short bf16x8;
typedef __attribute__((ext_vector_type(4))) float f32x4;

static __device__ __forceinline__ unsigned short f2bf(float f) {
  union { float f; unsigned int u; } v; v.f = f;
  unsigned int u = v.u;
  unsigned int r = u + 0x7FFFu + ((u >> 16) & 1u);   // RTNE
  return (unsigned short)(r >> 16);
}
static __device__ __forceinline__ float bf2f(unsigned short s) {
  union { unsigned int u; float f; } v; v.u = ((unsigned int)s) << 16;
  return v.f;
}

// async global->LDS, 16B per lane; lds dest = wave-uniform base + lane*16
#define GLD16(g, l) __builtin_amdgcn_global_load_lds( \
    (const __attribute__((address_space(1))) void*)(g), \
    (__attribute__((address_space(3))) void*)(l), 16, 0, 0)

// ------- x fp32 -> bf16 (+optional out=residual init, + cnt zeroing) -------
__global__ __launch_bounds__(256) void convert_x(const float4* __restrict__ x4,
                                                 ushort4* __restrict__ xb4,
                                                 float4* __restrict__ out4,
                                                 int* __restrict__ cnt, int initOut) {
  int i = blockIdx.x * 256 + threadIdx.x;
  if (blockIdx.x == 0 && threadIdx.x < 16) cnt[threadIdx.x] = 0;
  float4 v = x4[i];
  if (initOut) out4[i] = v;
  ushort4 o;
  o.x = f2bf(v.x); o.y = f2bf(v.y); o.z = f2bf(v.z); o.w = f2bf(v.w);
  xb4[i] = o;
}

// ---------------- all 27 weight matrices: fp32 [K][N] -> bf16 [N][K] -------
struct SrcPtrs { const float* p[6]; };

__global__ __launch_bounds__(256) void transpose_all(SrcPtrs S,
                                                     unsigned short* __restrict__ dstBase) {
  const int z = blockIdx.z;
  const float* src; int dz;
  if (z == 0)      { src = S.p[0];                              dz = 8;  }
  else if (z == 1) { src = S.p[1];                              dz = 17; }
  else if (z == 2) { src = S.p[2];                              dz = 26; }
  else if (z < 11) { src = S.p[3] + (size_t)(z - 3)  * 1048576; dz = z - 3; }
  else if (z < 19) { src = S.p[4] + (size_t)(z - 11) * 1048576; dz = 9 + (z - 11); }
  else             { src = S.p[5] + (size_t)(z - 19) * 1048576; dz = 18 + (z - 19); }
  unsigned short* dst = dstBase + (size_t)dz * 1048576;

  const int tid = threadIdx.x;
  const int rid = tid & 7;
  const int cid = tid >> 3;
  const int r = blockIdx.y * 64 + rid * 8;
  const int c = blockIdx.x * 128 + cid * 4;

  float4 v[8];
#pragma unroll
  for (int i = 0; i < 8; i++)
    v[i] = *(const float4*)&src[(size_t)(r + i) * 1024 + c];

#pragma unroll
  for (int j = 0; j < 4; j++) {
    unsigned short o[8];
    o[0] = f2bf(v[0][j]); o[1] = f2bf(v[1][j]);
    o[2] = f2bf(v[2][j]); o[3] = f2bf(v[3][j]);
    o[4] = f2bf(v[4][j]); o[5] = f2bf(v[5][j]);
    o[6] = f2bf(v[6][j]); o[7] = f2bf(v[7][j]);
    *(bf16x8*)&dst[(size_t)(c + j) * 1024 + r] = *(const bf16x8*)o;
  }
}

// ---------------- router: tiled fp32 logits + softmax + top2 ----------------
__global__ __launch_bounds__(256) void router2(
    const float* __restrict__ x, const float* __restrict__ rw,
    int* __restrict__ cnt, int* __restrict__ list, float* __restrict__ wgt) {
  __shared__ float rwT[1024 * 8];
  const int tid = threadIdx.x;
#pragma unroll
  for (int c = 0; c < 4; c++) {
    const int h = c * 256 + tid;
    float v[8];
#pragma unroll
    for (int e = 0; e < EDIM; e++) v[e] = rw[e * 1024 + h];
    *(float4*)&rwT[h * 8]     = make_float4(v[0], v[1], v[2], v[3]);
    *(float4*)&rwT[h * 8 + 4] = make_float4(v[4], v[5], v[6], v[7]);
  }
  __syncthreads();

  const int tt = tid >> 4;
  const int pp = tid & 15;
  const int t = blockIdx.x * 16 + tt;
  const float* xr = x + (size_t)t * HDIM;

  float a[EDIM];
#pragma unroll
  for (int e = 0; e < EDIM; e++) a[e] = 0.f;

#pragma unroll 8
  for (int i = 0; i < 64; i++) {
    const int h = pp + 16 * i;
    const float xs = xr[h];
    const float4 r0 = *(const float4*)&rwT[h * 8];
    const float4 r1 = *(const float4*)&rwT[h * 8 + 4];
    a[0] += xs * r0.x; a[1] += xs * r0.y; a[2] += xs * r0.z; a[3] += xs * r0.w;
    a[4] += xs * r1.x; a[5] += xs * r1.y; a[6] += xs * r1.z; a[7] += xs * r1.w;
  }
#pragma unroll
  for (int s = 1; s < 16; s <<= 1) {
#pragma unroll
    for (int e = 0; e < EDIM; e++) a[e] += __shfl_xor(a[e], s, 16);
  }
  if (pp == 0) {
    float m = a[0];
#pragma unroll
    for (int e = 1; e < EDIM; e++) m = fmaxf(m, a[e]);
    float p[EDIM]; float s = 0.f;
#pragma unroll
    for (int e = 0; e < EDIM; e++) { p[e] = expf(a[e] - m); s += p[e]; }
    float inv = 1.f / s;
    int e1 = 0; float b1 = p[0];
#pragma unroll
    for (int e = 1; e < EDIM; e++) if (p[e] > b1) { b1 = p[e]; e1 = e; }
    int e2 = -1; float b2 = -1.f;
#pragma unroll
    for (int e = 0; e < EDIM; e++) if (e != e1 && p[e] > b2) { b2 = p[e]; e2 = e; }
    int pos1 = atomicAdd(&cnt[e1], 1);
    list[e1 * T_TOK + pos1] = (t << 1);      wgt[e1 * T_TOK + pos1] = b1 * inv;
    int pos2 = atomicAdd(&cnt[e2], 1);
    list[e2 * T_TOK + pos2] = (t << 1) | 1;  wgt[e2 * T_TOK + pos2] = b2 * inv;
  }
}

// ============================================================================
// 256x256x64 8-phase GEMM kernels (gateup8 / down8)
// 512 thr = 8 waves (2m x 4n), wave out 128x64, LDS 128KB (2 K-tile dbuf).
// Per K-tile: 4 phases, quads (0,0)(1,0)(1,1)(0,1); reads {12,8,4,0} b128;
// 1 half-region staged per phase; vmcnt(6) once per tile (never 0 in loop).
// Regions: A-half h = rows with bit6==h ({0-63,128-191} / rest);
//          B-half h = rows with bit5==h. Stage of a region happens >=1 phase
//          after the last phase that ds_reads it (reads retire via lgkmcnt(0)
//          before that phase's end barrier) -> no LDS WAR race.
// Chunk swizzle: LDS[row][c] holds global k-chunk c ^ (row&7) (involution on
// both stage-source and read side).
// ============================================================================

// ---------------- fused gate/up (z=0..7 routed, z=8 shared) -----------------
__global__ __launch_bounds__(512, 2) void gateup8(
    const unsigned short* __restrict__ xb,
    const unsigned short* __restrict__ gateT,
    const unsigned short* __restrict__ upT,
    unsigned short* __restrict__ hid,
    const int* __restrict__ cnt, const int* __restrict__ list) {
  __shared__ __align__(16) unsigned short As[2][256 * 64];  // 64 KB
  __shared__ __align__(16) unsigned short Bs[2][256 * 64];  // 64 KB

  const int tid = threadIdx.x;
  const int lane = tid & 63;
  const int w = tid >> 6;        // 0..7
  const int wm = w >> 2;         // 0..1
  const int wn = w & 3;          // 0..3
  const int z = blockIdx.z;
  const int m0 = blockIdx.y * 256;
  const int n0 = blockIdx.x * 128;   // I-cols

  int count, hidbase;
  if (z < EDIM) {
    count = cnt[z];
    if (m0 >= count) return;
    int off = 0;
#pragma unroll
    for (int i = 0; i < EDIM; i++) off += (i < z) ? cnt[i] : 0;
    hidbase = off;
  } else {
    count = T_TOK;
    hidbase = HID_SHARED_BASE;
  }

  const int l3 = lane >> 3;                      // 0..7
  const unsigned g8 = (unsigned)(((lane & 7) ^ l3) * 8);  // swizzled k-chunk

  // staging source offsets (elements). A rows: r*128 + h*64 + w*8 + l3
  // B rows: (w>>1)*64 + h*32 + ((w&1)*2+r)*8 + l3
  unsigned aOff[2][2], bOff[2][2];
#pragma unroll
  for (int h = 0; h < 2; h++) {
#pragma unroll
    for (int r = 0; r < 2; r++) {
      const int rowA = r * 128 + h * 64 + w * 8 + l3;
      int tok;
      if (z < EDIM) {
        int p = m0 + rowA; if (p >= count) p = count - 1;
        tok = list[z * T_TOK + p] >> 1;
      } else tok = m0 + rowA;
      aOff[h][r] = (unsigned)tok * 1024u + g8;

      const int rowB = (w >> 1) * 64 + h * 32 + ((w & 1) * 2 + r) * 8 + l3;
      const int grp = rowB >> 5, ud = (rowB >> 4) & 1, cc = rowB & 15;
      const unsigned icol = (unsigned)(n0 + grp * 16 + cc);
      bOff[h][r] = (unsigned)ud * 9437184u + icol * 1024u + g8;  // upT = gateT + 9M
    }
  }
  const unsigned short* aBase = xb;
  const unsigned short* bBase = gateT + (size_t)z * (HDIM * IDIM);

  auto stageA = [&](int buf, int kt, int h) {
#pragma unroll
    for (int r = 0; r < 2; r++)
      GLD16(aBase + aOff[h][r] + kt * 64,
            &As[buf][(r * 128 + h * 64 + w * 8) * 64]);
  };
  auto stageB = [&](int buf, int kt, int h) {
#pragma unroll
    for (int r = 0; r < 2; r++)
      GLD16(bBase + bOff[h][r] + kt * 64,
            &Bs[buf][((w >> 1) * 64 + h * 32 + ((w & 1) * 2 + r) * 8) * 64]);
  };

  const int q = lane >> 4;
  const int r16 = lane & 15;
  const int rsw = r16 & 7;

  bf16x8 a0[8], a1[8], b0[4], b1[4];
  auto readA = [&](int buf, int mh, bf16x8 (&dst)[8]) {
#pragma unroll
    for (int i = 0; i < 4; i++)
#pragma unroll
      for (int kk = 0; kk < 2; kk++)
        dst[i * 2 + kk] = *(const bf16x8*)&As[buf][
            (wm * 128 + mh * 64 + i * 16 + r16) * 64 + (((kk * 4 + q) ^ rsw) * 8)];
  };
  auto readB = [&](int buf, int nh, bf16x8 (&dst)[4]) {
#pragma unroll
    for (int j = 0; j < 2; j++)
#pragma unroll
      for (int kk = 0; kk < 2; kk++)
        dst[j * 2 + kk] = *(const bf16x8*)&Bs[buf][
            (wn * 64 + nh * 32 + j * 16 + r16) * 64 + (((kk * 4 + q) ^ rsw) * 8)];
  };

  f32x4 acc[8][4];
  const f32x4 z4 = {0.f, 0.f, 0.f, 0.f};
#pragma unroll
  for (int i = 0; i < 8; i++)
#pragma unroll
    for (int j = 0; j < 4; j++) acc[i][j] = z4;

  auto quad = [&](const bf16x8 (&A)[8], const bf16x8 (&B)[4], int mh, int nh) {
#pragma unroll
    for (int i = 0; i < 4; i++)
#pragma unroll
      for (int j = 0; j < 2; j++)
#pragma unroll
        for (int kk = 0; kk < 2; kk++)
          acc[mh * 4 + i][nh * 2 + j] = __builtin_amdgcn_mfma_f32_16x16x32_bf16(
              A[i * 2 + kk], B[j * 2 + kk], acc[mh * 4 + i][nh * 2 + j], 0, 0, 0);
  };

  const int NT = 16;
  // prologue: tile0 {A0,A1,B0,B1}, tile1 {A0,A1,B0}  (Bh1(1) staged at phase A(0))
  stageA(0, 0, 0); stageA(0, 0, 1); stageB(0, 0, 0); stageB(0, 0, 1);
  stageA(1, 1, 0); stageA(1, 1, 1); stageB(1, 1, 0);
  asm volatile("s_waitcnt vmcnt(6)" ::: "memory");
  __builtin_amdgcn_s_barrier();

#pragma unroll 1
  for (int kt = 0; kt < NT; kt++) {
    const int buf = kt & 1;
    // ---- phase A: quad(0,0) ----
    readA(buf, 0, a0);
    readB(buf, 0, b0);
    if (kt + 1 < NT) stageB(buf ^ 1, kt + 1, 1);
    asm volatile("s_waitcnt lgkmcnt(0)" ::: "memory");
    __builtin_amdgcn_s_setprio(1);
    quad(a0, b0, 0, 0);
    __builtin_amdgcn_s_setprio(0);
    __builtin_amdgcn_s_barrier();
    // ---- phase B: quad(1,0) ----
    readA(buf, 1, a1);
    if (kt + 2 < NT) stageA(buf, kt + 2, 0);
    asm volatile("s_waitcnt lgkmcnt(0)" ::: "memory");
    __builtin_amdgcn_s_setprio(1);
    quad(a1, b0, 1, 0);
    __builtin_amdgcn_s_setprio(0);
    __builtin_amdgcn_s_barrier();
    // ---- phase C: quad(1,1) ----
    readB(buf, 1, b1);
    if (kt + 2 < NT) stageA(buf, kt + 2, 1);
    asm volatile("s_waitcnt lgkmcnt(0)" ::: "memory");
    __builtin_amdgcn_s_setprio(1);
    quad(a1, b1, 1, 1);
    __builtin_amdgcn_s_setprio(0);
    __builtin_amdgcn_s_barrier();
    // ---- phase D: quad(0,1) ----
    if (kt + 2 < NT) stageB(buf, kt + 2, 0);
    __builtin_amdgcn_s_setprio(1);
    quad(a0, b1, 0, 1);
    __builtin_amdgcn_s_setprio(0);
    if (kt + 2 < NT) { asm volatile("s_waitcnt vmcnt(6)" ::: "memory"); }
    else             { asm volatile("s_waitcnt vmcnt(0)" ::: "memory"); }
    __builtin_amdgcn_s_barrier();
  }

  // epilogue: acc[i][nh*2]=gate, acc[i][nh*2+1]=up at icol=n0+(wn*2+nh)*16+r16
#pragma unroll
  for (int i = 0; i < 8; i++) {
#pragma unroll
    for (int nh = 0; nh < 2; nh++) {
      const int icol = n0 + (wn * 2 + nh) * 16 + r16;
      f32x4 g4 = acc[i][nh * 2 + 0];
      f32x4 u4 = acc[i][nh * 2 + 1];
#pragma unroll
      for (int r = 0; r < 4; r++) {
        const int pos = m0 + wm * 128 + i * 16 + q * 4 + r;
        if (pos < count) {
          float h = u4[r] / (1.f + __expf(-g4[r]));
          hid[(size_t)(hidbase + pos) * IDIM + icol] = f2bf(h);
        }
      }
    }
  }
}

// ---------------- fused down (z=0..7 routed, z=8 shared) --------------------
__global__ __launch_bounds__(512, 2) void down8(
    const unsigned short* __restrict__ hid,
    const unsigned short* __restrict__ downT,
    float* __restrict__ out, unsigned short* __restrict__ R, int useR,
    const int* __restrict__ cnt, const int* __restrict__ list,
    const float* __restrict__ wgt) {
  __shared__ __align__(16) unsigned short As[2][256 * 64];  // 64 KB
  __shared__ __align__(16) unsigned short Bs[2][256 * 64];  // 64 KB

  const int tid = threadIdx.x;
  const int lane = tid & 63;
  const int w = tid >> 6;
  const int wm = w >> 2;
  const int wn = w & 3;
  const int z = blockIdx.z;
  const int m0 = blockIdx.y * 256;
  const int n0 = blockIdx.x * 256;   // H-cols

  int count, abase;
  if (z < EDIM) {
    count = cnt[z];
    if (m0 >= count) return;
    int off = 0;
#pragma unroll
    for (int i = 0; i < EDIM; i++) off += (i < z) ? cnt[i] : 0;
    abase = off;
  } else {
    count = T_TOK;
    abase = HID_SHARED_BASE;
  }

  const int l3 = lane >> 3;
  const unsigned g8 = (unsigned)(((lane & 7) ^ l3) * 8);

  unsigned aOff[2][2], bOff[2][2];
#pragma unroll
  for (int h = 0; h < 2; h++) {
#pragma unroll
    for (int r = 0; r < 2; r++) {
      const int rowA = r * 128 + h * 64 + w * 8 + l3;
      aOff[h][r] = (unsigned)(abase + m0 + rowA) * 1024u + g8;
      const int rowB = (w >> 1) * 64 + h * 32 + ((w & 1) * 2 + r) * 8 + l3;
      bOff[h][r] = (unsigned)(n0 + rowB) * 1024u + g8;
    }
  }
  const unsigned short* aBase = hid;
  const unsigned short* bBase = downT + (size_t)z * (IDIM * HDIM);

  auto stageA = [&](int buf, int kt, int h) {
#pragma unroll
    for (int r = 0; r < 2; r++)
      GLD16(aBase + aOff[h][r] + kt * 64,
            &As[buf][(r * 128 + h * 64 + w * 8) * 64]);
  };
  auto stageB = [&](int buf, int kt, int h) {
#pragma unroll
    for (int r = 0; r < 2; r++)
      GLD16(bBase + bOff[h][r] + kt * 64,
            &Bs[buf][((w >> 1) * 64 + h * 32 + ((w & 1) * 2 + r) * 8) * 64]);
  };

  const int q = lane >> 4;
  const int r16 = lane & 15;
  const int rsw = r16 & 7;

  bf16x8 a0[8], a1[8], b0[4], b1[4];
  auto readA = [&](int buf, int mh, bf16x8 (&dst)[8]) {
#pragma unroll
    for (int i = 0; i < 4; i++)
#pragma unroll
      for (int kk = 0; kk < 2; kk++)
        dst[i * 2 + kk] = *(const bf16x8*)&As[buf][
            (wm * 128 + mh * 64 + i * 16 + r16) * 64 + (((kk * 4 + q) ^ rsw) * 8)];
  };
  auto readB = [&](int buf, int nh, bf16x8 (&dst)[4]) {
#pragma unroll
    for (int j = 0; j < 2; j++)
#pragma unroll
      for (int kk = 0; kk < 2; kk++)
        dst[j * 2 + kk] = *(const bf16x8*)&Bs[buf][
            (wn * 64 + nh * 32 + j * 16 + r16) * 64 + (((kk * 4 + q) ^ rsw) * 8)];
  };

  f32x4 acc[8][4];
  const f32x4 z4 = {0.f, 0.f, 0.f, 0.f};
#pragma unroll
  for (int i = 0; i < 8; i++)
#pragma unroll
    for (int j = 0; j < 4; j++) acc[i][j] = z4;

  auto quad = [&](const bf16x8 (&A)[8], const bf16x8 (&B)[4], int mh, int nh) {
#pragma unroll
    for (int i = 0; i < 4; i++)
#pragma unroll
      for (int j = 0; j < 2; j++)
#pragma unroll
        for (int kk = 0; kk < 2; kk++)
          acc[mh * 4 + i][nh * 2 + j] = __builtin_amdgcn_mfma_f32_16x16x32_bf16(
              A[i * 2 + kk], B[j * 2 + kk], acc[mh * 4 + i][nh * 2 + j], 0, 0, 0);
  };

  const int NT = 16;
  stageA(0, 0, 0); stageA(0, 0, 1); stageB(0, 0, 0); stageB(0, 0, 1);
  stageA(1, 1, 0); stageA(1, 1, 1); stageB(1, 1, 0);
  asm volatile("s_waitcnt vmcnt(6)" ::: "memory");
  __builtin_amdgcn_s_barrier();

#pragma unroll 1
  for (int kt = 0; kt < NT; kt++) {
    const int buf = kt & 1;
    readA(buf, 0, a0);
    readB(buf, 0, b0);
    if (kt + 1 < NT) stageB(buf ^ 1, kt + 1, 1);
    asm volatile("s_waitcnt lgkmcnt(0)" ::: "memory");
    __builtin_amdgcn_s_setprio(1);
    quad(a0, b0, 0, 0);
    __builtin_amdgcn_s_setprio(0);
    __builtin_amdgcn_s_barrier();

    readA(buf, 1, a1);
    if (kt + 2 < NT) stageA(buf, kt + 2, 0);
    asm volatile("s_waitcnt lgkmcnt(0)" ::: "memory");
    __builtin_amdgcn_s_setprio(1);
    quad(a1, b0, 1, 0);
    __builtin_amdgcn_s_setprio(0);
    __builtin_amdgcn_s_barrier();

    readB(buf, 1, b1);
    if (kt + 2 < NT) stageA(buf, kt + 2, 1);
    asm volatile("s_waitcnt lgkmcnt(0)" ::: "memory");
    __builtin_amdgcn_s_setprio(1);
    quad(a1, b1, 1, 1);
    __builtin_amdgcn_s_setprio(0);
    __builtin_amdgcn_s_barrier();

    if (kt + 2 < NT) stageB(buf, kt + 2, 0);
    __builtin_amdgcn_s_setprio(1);
    quad(a0, b1, 0, 1);
    __builtin_amdgcn_s_setprio(0);
    if (kt + 2 < NT) { asm volatile("s_waitcnt vmcnt(6)" ::: "memory"); }
    else             { asm volatile("s_waitcnt vmcnt(0)" ::: "memory"); }
    __builtin_amdgcn_s_barrier();
  }

#pragma unroll
  for (int i = 0; i < 8; i++) {
    int toks[4]; int slot[4]; float ws4[4];
#pragma unroll
    for (int r = 0; r < 4; r++) {
      const int pos = m0 + wm * 128 + i * 16 + q * 4 + r;
      if (z < EDIM) {
        bool ok = pos < count;
        int v = ok ? list[z * T_TOK + pos] : -2;
        toks[r] = v >> 1; slot[r] = v & 1;
        ws4[r] = ok ? wgt[z * T_TOK + pos] : 0.f;
      } else {
        toks[r] = pos; slot[r] = 2; ws4[r] = 1.f;
      }
    }
#pragma unroll
    for (int j = 0; j < 4; j++) {
      const int col = n0 + wn * 64 + (j >> 1) * 32 + (j & 1) * 16 + r16;
#pragma unroll
      for (int r = 0; r < 4; r++) {
        if (toks[r] >= 0) {
          float v = ws4[r] * acc[i][j][r];
          if (useR) {
            R[((size_t)toks[r] * 3 + slot[r]) * HDIM + col] = f2bf(v);
          } else {
            atomicAdd(&out[(size_t)toks[r] * HDIM + col], v);
          }
        }
      }
    }
  }
}

// ---------------- final combine: out = x + R0 + R1 + R2 ---------------------
__global__ __launch_bounds__(256) void combine_k(const float4* __restrict__ x4,
                                                 const unsigned short* __restrict__ R,
                                                 float4* __restrict__ out4) {
  const int i8 = blockIdx.x * 256 + threadIdx.x;
  const int t = i8 >> 7;
  const int c8 = (i8 & 127) * 8;
  const unsigned short* r0 = R + ((size_t)t * 3) * 1024 + c8;
  float s[8];
#pragma unroll
  for (int k = 0; k < 8; k++) s[k] = 0.f;
#pragma unroll
  for (int sl = 0; sl < 3; sl++) {
    bf16x8 v = *(const bf16x8*)(r0 + sl * 1024);
#pragma unroll
    for (int k = 0; k < 8; k++) s[k] += bf2f(((const unsigned short*)&v)[k]);
  }
  float4 a = x4[i8 * 2], b = x4[i8 * 2 + 1];
  a.x += s[0]; a.y += s[1]; a.z += s[2]; a.w += s[3];
  b.x += s[4]; b.y += s[5]; b.z += s[6]; b.w += s[7];
  out4[i8 * 2] = a;
  out4[i8 * 2 + 1] = b;
}

extern "C" void kernel_launch(void* const* d_in, const int* in_sizes, int n_in,
                              void* d_out, int out_size, void* d_ws, size_t ws_size,
                              hipStream_t stream) {
  const float* x  = (const float*)d_in[0];
  const float* rw = (const float*)d_in[1];
  const float* sg = (const float*)d_in[2];
  const float* su = (const float*)d_in[3];
  const float* sd = (const float*)d_in[4];
  const float* eg = (const float*)d_in[5];
  const float* eu = (const float*)d_in[6];
  const float* ed = (const float*)d_in[7];
  float* out = (float*)d_out;

  char* ws = (char*)d_ws;
  unsigned short* xb  = (unsigned short*)ws;                          // 8 MB
  unsigned short* hid = xb + (size_t)T_TOK * HDIM;                    // 25.4 MB
  int*   cnt  = (int*)(hid + (size_t)(HID_SHARED_BASE + T_TOK) * IDIM);
  int*   list = cnt + 16;
  float* wgt  = (float*)(list + EDIM * T_TOK);
  unsigned short* wT    = (unsigned short*)(wgt + EDIM * T_TOK);      // 54 MB
  unsigned short* gateT = wT;
  unsigned short* upT   = wT + (size_t)9 * 1048576;
  unsigned short* downT = wT + (size_t)18 * 1048576;
  unsigned short* R = wT + (size_t)27 * 1048576;                      // 25 MB
  size_t need = ((char*)(R + (size_t)T_TOK * 3 * HDIM)) - ws;
  const int useR = (ws_size >= need) ? 1 : 0;

  convert_x<<<(T_TOK * HDIM) / 1024, 256, 0, stream>>>(
      (const float4*)x, (ushort4*)xb, (float4*)out, cnt, useR ? 0 : 1);
  router2<<<T_TOK / 16, 256, 0, stream>>>(x, rw, cnt, list, wgt);

  SrcPtrs S; S.p[0] = sg; S.p[1] = su; S.p[2] = sd; S.p[3] = eg; S.p[4] = eu; S.p[5] = ed;
  transpose_all<<<dim3(8, 16, 27), 256, 0, stream>>>(S, wT);

  gateup8<<<dim3(IDIM / 128, 16, 9), 512, 0, stream>>>(xb, gateT, upT, hid, cnt, list);
  down8<<<dim3(HDIM / 256, 16, 9), 512, 0, stream>>>(hid, downT, out, R, useR,
                                                     cnt, list, wgt);
  if (useR) {
    combine_k<<<(T_TOK * HDIM / 8) / 256, 256, 0, stream>>>(
        (const float4*)x, R, (float4*)out);
  }
}

// Round 2
// 367.682 us; speedup vs baseline: 1.0469x; 1.0469x over previous
//
#include <hip/hip_runtime.h>
#include <hip/hip_bf16.h>

#define T_TOK 4096
#define HDIM 1024
#define IDIM 1024
#define EDIM 8
#define HID_SHARED_BASE 8320   // routed hid rows [0,8320); shared at [8320,12416)

typedef __attribute__((ext_vector_type(8))) short bf16x8;
typedef __attribute__((ext_vector_type(4))) float f32x4;

static __device__ __forceinline__ unsigned short f2bf(float f) {
  union { float f; unsigned int u; } v; v.f = f;
  unsigned int u = v.u;
  unsigned int r = u + 0x7FFFu + ((u >> 16) & 1u);   // RTNE
  return (unsigned short)(r >> 16);
}
static __device__ __forceinline__ float bf2f(unsigned short s) {
  union { unsigned int u; float f; } v; v.u = ((unsigned int)s) << 16;
  return v.f;
}

// async global->LDS, 16B per lane; lds dest = wave-uniform base + lane*16
#define GLD16(g, l) __builtin_amdgcn_global_load_lds( \
    (const __attribute__((address_space(1))) void*)(g), \
    (__attribute__((address_space(3))) void*)(l), 16, 0, 0)

// ------- x fp32 -> bf16 (+optional out=residual init, + cnt zeroing) -------
__global__ __launch_bounds__(256) void convert_x(const float4* __restrict__ x4,
                                                 ushort4* __restrict__ xb4,
                                                 float4* __restrict__ out4,
                                                 int* __restrict__ cnt, int initOut) {
  int i = blockIdx.x * 256 + threadIdx.x;
  if (blockIdx.x == 0 && threadIdx.x < 16) cnt[threadIdx.x] = 0;
  float4 v = x4[i];
  if (initOut) out4[i] = v;
  ushort4 o;
  o.x = f2bf(v.x); o.y = f2bf(v.y); o.z = f2bf(v.z); o.w = f2bf(v.w);
  xb4[i] = o;
}

// ---------------- all 27 weight matrices: fp32 [K][N] -> bf16 [N][K] -------
struct SrcPtrs { const float* p[6]; };

__global__ __launch_bounds__(256) void transpose_all(SrcPtrs S,
                                                     unsigned short* __restrict__ dstBase) {
  const int z = blockIdx.z;
  const float* src; int dz;
  if (z == 0)      { src = S.p[0];                              dz = 8;  }
  else if (z == 1) { src = S.p[1];                              dz = 17; }
  else if (z == 2) { src = S.p[2];                              dz = 26; }
  else if (z < 11) { src = S.p[3] + (size_t)(z - 3)  * 1048576; dz = z - 3; }
  else if (z < 19) { src = S.p[4] + (size_t)(z - 11) * 1048576; dz = 9 + (z - 11); }
  else             { src = S.p[5] + (size_t)(z - 19) * 1048576; dz = 18 + (z - 19); }
  unsigned short* dst = dstBase + (size_t)dz * 1048576;

  const int tid = threadIdx.x;
  const int rid = tid & 7;
  const int cid = tid >> 3;
  const int r = blockIdx.y * 64 + rid * 8;
  const int c = blockIdx.x * 128 + cid * 4;

  float4 v[8];
#pragma unroll
  for (int i = 0; i < 8; i++)
    v[i] = *(const float4*)&src[(size_t)(r + i) * 1024 + c];

#pragma unroll
  for (int j = 0; j < 4; j++) {
    unsigned short o[8];
    o[0] = f2bf(v[0][j]); o[1] = f2bf(v[1][j]);
    o[2] = f2bf(v[2][j]); o[3] = f2bf(v[3][j]);
    o[4] = f2bf(v[4][j]); o[5] = f2bf(v[5][j]);
    o[6] = f2bf(v[6][j]); o[7] = f2bf(v[7][j]);
    *(bf16x8*)&dst[(size_t)(c + j) * 1024 + r] = *(const bf16x8*)o;
  }
}

// ---------------- router: tiled fp32 logits + softmax + top2 ----------------
__global__ __launch_bounds__(256) void router2(
    const float* __restrict__ x, const float* __restrict__ rw,
    int* __restrict__ cnt, int* __restrict__ list, float* __restrict__ wgt) {
  __shared__ float rwT[1024 * 8];
  const int tid = threadIdx.x;
#pragma unroll
  for (int c = 0; c < 4; c++) {
    const int h = c * 256 + tid;
    float v[8];
#pragma unroll
    for (int e = 0; e < EDIM; e++) v[e] = rw[e * 1024 + h];
    *(float4*)&rwT[h * 8]     = make_float4(v[0], v[1], v[2], v[3]);
    *(float4*)&rwT[h * 8 + 4] = make_float4(v[4], v[5], v[6], v[7]);
  }
  __syncthreads();

  const int tt = tid >> 4;
  const int pp = tid & 15;
  const int t = blockIdx.x * 16 + tt;
  const float* xr = x + (size_t)t * HDIM;

  float a[EDIM];
#pragma unroll
  for (int e = 0; e < EDIM; e++) a[e] = 0.f;

#pragma unroll 8
  for (int i = 0; i < 64; i++) {
    const int h = pp + 16 * i;
    const float xs = xr[h];
    const float4 r0 = *(const float4*)&rwT[h * 8];
    const float4 r1 = *(const float4*)&rwT[h * 8 + 4];
    a[0] += xs * r0.x; a[1] += xs * r0.y; a[2] += xs * r0.z; a[3] += xs * r0.w;
    a[4] += xs * r1.x; a[5] += xs * r1.y; a[6] += xs * r1.z; a[7] += xs * r1.w;
  }
#pragma unroll
  for (int s = 1; s < 16; s <<= 1) {
#pragma unroll
    for (int e = 0; e < EDIM; e++) a[e] += __shfl_xor(a[e], s, 16);
  }
  if (pp == 0) {
    float m = a[0];
#pragma unroll
    for (int e = 1; e < EDIM; e++) m = fmaxf(m, a[e]);
    float p[EDIM]; float s = 0.f;
#pragma unroll
    for (int e = 0; e < EDIM; e++) { p[e] = expf(a[e] - m); s += p[e]; }
    float inv = 1.f / s;
    int e1 = 0; float b1 = p[0];
#pragma unroll
    for (int e = 1; e < EDIM; e++) if (p[e] > b1) { b1 = p[e]; e1 = e; }
    int e2 = -1; float b2 = -1.f;
#pragma unroll
    for (int e = 0; e < EDIM; e++) if (e != e1 && p[e] > b2) { b2 = p[e]; e2 = e; }
    int pos1 = atomicAdd(&cnt[e1], 1);
    list[e1 * T_TOK + pos1] = (t << 1);      wgt[e1 * T_TOK + pos1] = b1 * inv;
    int pos2 = atomicAdd(&cnt[e2], 1);
    list[e2 * T_TOK + pos2] = (t << 1) | 1;  wgt[e2 * T_TOK + pos2] = b2 * inv;
  }
}

// ============================================================================
// 128x{64I-pair|128}x64 4-phase GEMM kernels, 256 thr (4 waves 2m x 2n),
// LDS 64KB -> 2 blocks/CU (cross-block TLP hides phase stalls).
// Per K-tile: 4 phases, quads (0,0)(1,0)(1,1)(0,1); reads {8,4,4,0} b128;
// 1 half-region staged per phase; vmcnt(6) once per tile (never 0 in loop).
// Regions by row bit5 (A: rows (rr>>5)*64 + h*32 + rr&31). Stage of a region
// happens >=1 phase after its last ds_read retires (lgkmcnt(0) before that
// phase's end barrier) -> no LDS WAR race (same proof as verified 256^2 ver).
// Chunk swizzle: LDS[row][c] holds global k-chunk c ^ (row&7) (involution on
// stage-source and read side; conflict-free, verified 0 SQ_LDS_BANK_CONFLICT).
// ============================================================================

// ---------------- fused gate/up (z=0..7 routed, z=8 shared) -----------------
__global__ __launch_bounds__(256, 2) void gateup9(
    const unsigned short* __restrict__ xb,
    const unsigned short* __restrict__ gateT,
    const unsigned short* __restrict__ upT,
    unsigned short* __restrict__ hid,
    const int* __restrict__ cnt, const int* __restrict__ list) {
  __shared__ __align__(16) unsigned short As[2][128 * 64];  // 32 KB
  __shared__ __align__(16) unsigned short Bs[2][128 * 64];  // 32 KB

  const int tid = threadIdx.x;
  const int lane = tid & 63;
  const int w = tid >> 6;        // 0..3
  const int wm = w >> 1;         // 0..1
  const int wn = w & 1;          // 0..1
  const int z = blockIdx.z;
  const int m0 = blockIdx.y * 128;
  const int n0 = blockIdx.x * 64;   // I-cols

  int count, hidbase;
  if (z < EDIM) {
    count = cnt[z];
    if (m0 >= count) return;
    int off = 0;
#pragma unroll
    for (int i = 0; i < EDIM; i++) off += (i < z) ? cnt[i] : 0;
    hidbase = off;
  } else {
    count = T_TOK;
    hidbase = HID_SHARED_BASE;
  }

  const int l3 = lane >> 3;                               // 0..7
  const unsigned g8 = (unsigned)(((lane & 7) ^ l3) * 8);  // swizzled k-chunk

  // staging source offsets. region row index rr = w*16 + j*8 + l3 (0..63)
  // A rows: (rr>>5)*64 + h*32 + (rr&31)   (row bit5 == h)
  // B rows: (h + 2*(rr>>5))*32 + (rr&31)  (grp = h or h+2; grp&1 == h)
  unsigned aOff[2][2], bOff[2][2];
#pragma unroll
  for (int h = 0; h < 2; h++) {
#pragma unroll
    for (int j = 0; j < 2; j++) {
      const int rr = w * 16 + j * 8 + l3;
      const int rowA = (rr >> 5) * 64 + h * 32 + (rr & 31);
      int tok;
      if (z < EDIM) {
        int p = m0 + rowA; if (p >= count) p = count - 1;
        tok = list[z * T_TOK + p] >> 1;
      } else tok = m0 + rowA;
      aOff[h][j] = (unsigned)tok * 1024u + g8;

      const int rowB = (h + 2 * (rr >> 5)) * 32 + (rr & 31);
      const int grp = rowB >> 5, ud = (rowB >> 4) & 1, cc = rowB & 15;
      const unsigned icol = (unsigned)(n0 + grp * 16 + cc);
      bOff[h][j] = (unsigned)ud * 9437184u + icol * 1024u + g8;  // upT = gateT + 9M
    }
  }
  const unsigned short* aBase = xb;
  const unsigned short* bBase = gateT + (size_t)z * (HDIM * IDIM);

  auto stageA = [&](int buf, int kt, int h) {
#pragma unroll
    for (int j = 0; j < 2; j++) {
      const int rr0 = w * 16 + j * 8;
      const int row0 = (rr0 >> 5) * 64 + h * 32 + (rr0 & 31);
      GLD16(aBase + aOff[h][j] + kt * 64, &As[buf][row0 * 64]);
    }
  };
  auto stageB = [&](int buf, int kt, int h) {
#pragma unroll
    for (int j = 0; j < 2; j++) {
      const int rr0 = w * 16 + j * 8;
      const int row0 = (h + 2 * (rr0 >> 5)) * 32 + (rr0 & 31);
      GLD16(bBase + bOff[h][j] + kt * 64, &Bs[buf][row0 * 64]);
    }
  };

  const int q = lane >> 4;
  const int r16 = lane & 15;
  const int rsw = r16 & 7;

  bf16x8 a0[4], a1[4], b0[4], b1[4];
  auto readA = [&](int buf, int mh, bf16x8 (&dst)[4]) {
#pragma unroll
    for (int i = 0; i < 2; i++)
#pragma unroll
      for (int kk = 0; kk < 2; kk++)
        dst[i * 2 + kk] = *(const bf16x8*)&As[buf][
            (wm * 64 + mh * 32 + i * 16 + r16) * 64 + (((kk * 4 + q) ^ rsw) * 8)];
  };
  auto readB = [&](int buf, int nh, bf16x8 (&dst)[4]) {
    const int grp = wn * 2 + nh;
#pragma unroll
    for (int ud = 0; ud < 2; ud++)
#pragma unroll
      for (int kk = 0; kk < 2; kk++)
        dst[ud * 2 + kk] = *(const bf16x8*)&Bs[buf][
            (grp * 32 + ud * 16 + r16) * 64 + (((kk * 4 + q) ^ rsw) * 8)];
  };

  f32x4 acc[4][2][2];   // [mi][nh][ud]
  const f32x4 z4 = {0.f, 0.f, 0.f, 0.f};
#pragma unroll
  for (int i = 0; i < 4; i++)
#pragma unroll
    for (int j = 0; j < 2; j++) { acc[i][j][0] = z4; acc[i][j][1] = z4; }

  auto quad = [&](const bf16x8 (&A)[4], const bf16x8 (&B)[4], int mh, int nh) {
#pragma unroll
    for (int i = 0; i < 2; i++)
#pragma unroll
      for (int ud = 0; ud < 2; ud++)
#pragma unroll
        for (int kk = 0; kk < 2; kk++)
          acc[mh * 2 + i][nh][ud] = __builtin_amdgcn_mfma_f32_16x16x32_bf16(
              A[i * 2 + kk], B[ud * 2 + kk], acc[mh * 2 + i][nh][ud], 0, 0, 0);
  };

  const int NT = 16;
  stageA(0, 0, 0); stageA(0, 0, 1); stageB(0, 0, 0); stageB(0, 0, 1);
  stageA(1, 1, 0); stageA(1, 1, 1); stageB(1, 1, 0);
  asm volatile("s_waitcnt vmcnt(6)" ::: "memory");
  __builtin_amdgcn_s_barrier();

#pragma unroll 1
  for (int kt = 0; kt < NT; kt++) {
    const int buf = kt & 1;
    // ---- phase A: quad(0,0) ----
    readA(buf, 0, a0);
    readB(buf, 0, b0);
    if (kt + 1 < NT) stageB(buf ^ 1, kt + 1, 1);
    asm volatile("s_waitcnt lgkmcnt(0)" ::: "memory");
    __builtin_amdgcn_s_setprio(1);
    quad(a0, b0, 0, 0);
    __builtin_amdgcn_s_setprio(0);
    __builtin_amdgcn_s_barrier();
    // ---- phase B: quad(1,0) ----
    readA(buf, 1, a1);
    if (kt + 2 < NT) stageA(buf, kt + 2, 0);
    asm volatile("s_waitcnt lgkmcnt(0)" ::: "memory");
    __builtin_amdgcn_s_setprio(1);
    quad(a1, b0, 1, 0);
    __builtin_amdgcn_s_setprio(0);
    __builtin_amdgcn_s_barrier();
    // ---- phase C: quad(1,1) ----
    readB(buf, 1, b1);
    if (kt + 2 < NT) stageA(buf, kt + 2, 1);
    asm volatile("s_waitcnt lgkmcnt(0)" ::: "memory");
    __builtin_amdgcn_s_setprio(1);
    quad(a1, b1, 1, 1);
    __builtin_amdgcn_s_setprio(0);
    __builtin_amdgcn_s_barrier();
    // ---- phase D: quad(0,1) ----
    if (kt + 2 < NT) stageB(buf, kt + 2, 0);
    __builtin_amdgcn_s_setprio(1);
    quad(a0, b1, 0, 1);
    __builtin_amdgcn_s_setprio(0);
    if (kt + 2 < NT) { asm volatile("s_waitcnt vmcnt(6)" ::: "memory"); }
    else             { asm volatile("s_waitcnt vmcnt(0)" ::: "memory"); }
    __builtin_amdgcn_s_barrier();
  }

  // epilogue: acc[mi][nh][0]=gate, acc[mi][nh][1]=up; icol = n0+(wn*2+nh)*16+r16
#pragma unroll
  for (int mi = 0; mi < 4; mi++) {
#pragma unroll
    for (int nh = 0; nh < 2; nh++) {
      const int icol = n0 + (wn * 2 + nh) * 16 + r16;
      f32x4 g4 = acc[mi][nh][0];
      f32x4 u4 = acc[mi][nh][1];
#pragma unroll
      for (int r = 0; r < 4; r++) {
        const int pos = m0 + wm * 64 + mi * 16 + q * 4 + r;
        if (pos < count) {
          float h = u4[r] / (1.f + __expf(-g4[r]));
          hid[(size_t)(hidbase + pos) * IDIM + icol] = f2bf(h);
        }
      }
    }
  }
}

// ---------------- fused down (z=0..7 routed, z=8 shared) --------------------
__global__ __launch_bounds__(256, 2) void down9(
    const unsigned short* __restrict__ hid,
    const unsigned short* __restrict__ downT,
    float* __restrict__ out, unsigned short* __restrict__ R, int useR,
    const int* __restrict__ cnt, const int* __restrict__ list,
    const float* __restrict__ wgt) {
  __shared__ __align__(16) unsigned short As[2][128 * 64];  // 32 KB
  __shared__ __align__(16) unsigned short Bs[2][128 * 64];  // 32 KB

  const int tid = threadIdx.x;
  const int lane = tid & 63;
  const int w = tid >> 6;
  const int wm = w >> 1;
  const int wn = w & 1;
  const int z = blockIdx.z;
  const int m0 = blockIdx.y * 128;
  const int n0 = blockIdx.x * 128;   // H-cols

  int count, abase;
  if (z < EDIM) {
    count = cnt[z];
    if (m0 >= count) return;
    int off = 0;
#pragma unroll
    for (int i = 0; i < EDIM; i++) off += (i < z) ? cnt[i] : 0;
    abase = off;
  } else {
    count = T_TOK;
    abase = HID_SHARED_BASE;
  }

  const int l3 = lane >> 3;
  const unsigned g8 = (unsigned)(((lane & 7) ^ l3) * 8);

  unsigned aOff[2][2], bOff[2][2];
#pragma unroll
  for (int h = 0; h < 2; h++) {
#pragma unroll
    for (int j = 0; j < 2; j++) {
      const int rr = w * 16 + j * 8 + l3;
      const int row = (rr >> 5) * 64 + h * 32 + (rr & 31);
      aOff[h][j] = (unsigned)(abase + m0 + row) * 1024u + g8;
      bOff[h][j] = (unsigned)(n0 + row) * 1024u + g8;
    }
  }
  const unsigned short* aBase = hid;
  const unsigned short* bBase = downT + (size_t)z * (IDIM * HDIM);

  auto stageA = [&](int buf, int kt, int h) {
#pragma unroll
    for (int j = 0; j < 2; j++) {
      const int rr0 = w * 16 + j * 8;
      const int row0 = (rr0 >> 5) * 64 + h * 32 + (rr0 & 31);
      GLD16(aBase + aOff[h][j] + kt * 64, &As[buf][row0 * 64]);
    }
  };
  auto stageB = [&](int buf, int kt, int h) {
#pragma unroll
    for (int j = 0; j < 2; j++) {
      const int rr0 = w * 16 + j * 8;
      const int row0 = (rr0 >> 5) * 64 + h * 32 + (rr0 & 31);
      GLD16(bBase + bOff[h][j] + kt * 64, &Bs[buf][row0 * 64]);
    }
  };

  const int q = lane >> 4;
  const int r16 = lane & 15;
  const int rsw = r16 & 7;

  bf16x8 a0[4], a1[4], b0[4], b1[4];
  auto readA = [&](int buf, int mh, bf16x8 (&dst)[4]) {
#pragma unroll
    for (int i = 0; i < 2; i++)
#pragma unroll
      for (int kk = 0; kk < 2; kk++)
        dst[i * 2 + kk] = *(const bf16x8*)&As[buf][
            (wm * 64 + mh * 32 + i * 16 + r16) * 64 + (((kk * 4 + q) ^ rsw) * 8)];
  };
  auto readB = [&](int buf, int nh, bf16x8 (&dst)[4]) {
#pragma unroll
    for (int j = 0; j < 2; j++)
#pragma unroll
      for (int kk = 0; kk < 2; kk++)
        dst[j * 2 + kk] = *(const bf16x8*)&Bs[buf][
            (wn * 64 + nh * 32 + j * 16 + r16) * 64 + (((kk * 4 + q) ^ rsw) * 8)];
  };

  f32x4 acc[4][2][2];   // [mi][nh][j]
  const f32x4 z4 = {0.f, 0.f, 0.f, 0.f};
#pragma unroll
  for (int i = 0; i < 4; i++)
#pragma unroll
    for (int j = 0; j < 2; j++) { acc[i][j][0] = z4; acc[i][j][1] = z4; }

  auto quad = [&](const bf16x8 (&A)[4], const bf16x8 (&B)[4], int mh, int nh) {
#pragma unroll
    for (int i = 0; i < 2; i++)
#pragma unroll
      for (int j = 0; j < 2; j++)
#pragma unroll
        for (int kk = 0; kk < 2; kk++)
          acc[mh * 2 + i][nh][j] = __builtin_amdgcn_mfma_f32_16x16x32_bf16(
              A[i * 2 + kk], B[j * 2 + kk], acc[mh * 2 + i][nh][j], 0, 0, 0);
  };

  const int NT = 16;
  stageA(0, 0, 0); stageA(0, 0, 1); stageB(0, 0, 0); stageB(0, 0, 1);
  stageA(1, 1, 0); stageA(1, 1, 1); stageB(1, 1, 0);
  asm volatile("s_waitcnt vmcnt(6)" ::: "memory");
  __builtin_amdgcn_s_barrier();

#pragma unroll 1
  for (int kt = 0; kt < NT; kt++) {
    const int buf = kt & 1;
    readA(buf, 0, a0);
    readB(buf, 0, b0);
    if (kt + 1 < NT) stageB(buf ^ 1, kt + 1, 1);
    asm volatile("s_waitcnt lgkmcnt(0)" ::: "memory");
    __builtin_amdgcn_s_setprio(1);
    quad(a0, b0, 0, 0);
    __builtin_amdgcn_s_setprio(0);
    __builtin_amdgcn_s_barrier();

    readA(buf, 1, a1);
    if (kt + 2 < NT) stageA(buf, kt + 2, 0);
    asm volatile("s_waitcnt lgkmcnt(0)" ::: "memory");
    __builtin_amdgcn_s_setprio(1);
    quad(a1, b0, 1, 0);
    __builtin_amdgcn_s_setprio(0);
    __builtin_amdgcn_s_barrier();

    readB(buf, 1, b1);
    if (kt + 2 < NT) stageA(buf, kt + 2, 1);
    asm volatile("s_waitcnt lgkmcnt(0)" ::: "memory");
    __builtin_amdgcn_s_setprio(1);
    quad(a1, b1, 1, 1);
    __builtin_amdgcn_s_setprio(0);
    __builtin_amdgcn_s_barrier();

    if (kt + 2 < NT) stageB(buf, kt + 2, 0);
    __builtin_amdgcn_s_setprio(1);
    quad(a0, b1, 0, 1);
    __builtin_amdgcn_s_setprio(0);
    if (kt + 2 < NT) { asm volatile("s_waitcnt vmcnt(6)" ::: "memory"); }
    else             { asm volatile("s_waitcnt vmcnt(0)" ::: "memory"); }
    __builtin_amdgcn_s_barrier();
  }

#pragma unroll
  for (int mi = 0; mi < 4; mi++) {
    int toks[4]; int slot[4]; float ws4[4];
#pragma unroll
    for (int r = 0; r < 4; r++) {
      const int pos = m0 + wm * 64 + mi * 16 + q * 4 + r;
      if (z < EDIM) {
        bool ok = pos < count;
        int v = ok ? list[z * T_TOK + pos] : -2;
        toks[r] = v >> 1; slot[r] = v & 1;
        ws4[r] = ok ? wgt[z * T_TOK + pos] : 0.f;
      } else {
        toks[r] = pos; slot[r] = 2; ws4[r] = 1.f;
      }
    }
#pragma unroll
    for (int nh = 0; nh < 2; nh++) {
#pragma unroll
      for (int j = 0; j < 2; j++) {
        const int col = n0 + wn * 64 + nh * 32 + j * 16 + r16;
#pragma unroll
        for (int r = 0; r < 4; r++) {
          if (toks[r] >= 0) {
            float v = ws4[r] * acc[mi][nh][j][r];
            if (useR) {
              R[((size_t)toks[r] * 3 + slot[r]) * HDIM + col] = f2bf(v);
            } else {
              atomicAdd(&out[(size_t)toks[r] * HDIM + col], v);
            }
          }
        }
      }
    }
  }
}

// ---------------- final combine: out = x + R0 + R1 + R2 ---------------------
__global__ __launch_bounds__(256) void combine_k(const float4* __restrict__ x4,
                                                 const unsigned short* __restrict__ R,
                                                 float4* __restrict__ out4) {
  const int i8 = blockIdx.x * 256 + threadIdx.x;
  const int t = i8 >> 7;
  const int c8 = (i8 & 127) * 8;
  const unsigned short* r0 = R + ((size_t)t * 3) * 1024 + c8;
  float s[8];
#pragma unroll
  for (int k = 0; k < 8; k++) s[k] = 0.f;
#pragma unroll
  for (int sl = 0; sl < 3; sl++) {
    bf16x8 v = *(const bf16x8*)(r0 + sl * 1024);
#pragma unroll
    for (int k = 0; k < 8; k++) s[k] += bf2f(((const unsigned short*)&v)[k]);
  }
  float4 a = x4[i8 * 2], b = x4[i8 * 2 + 1];
  a.x += s[0]; a.y += s[1]; a.z += s[2]; a.w += s[3];
  b.x += s[4]; b.y += s[5]; b.z += s[6]; b.w += s[7];
  out4[i8 * 2] = a;
  out4[i8 * 2 + 1] = b;
}

extern "C" void kernel_launch(void* const* d_in, const int* in_sizes, int n_in,
                              void* d_out, int out_size, void* d_ws, size_t ws_size,
                              hipStream_t stream) {
  const float* x  = (const float*)d_in[0];
  const float* rw = (const float*)d_in[1];
  const float* sg = (const float*)d_in[2];
  const float* su = (const float*)d_in[3];
  const float* sd = (const float*)d_in[4];
  const float* eg = (const float*)d_in[5];
  const float* eu = (const float*)d_in[6];
  const float* ed = (const float*)d_in[7];
  float* out = (float*)d_out;

  char* ws = (char*)d_ws;
  unsigned short* xb  = (unsigned short*)ws;                          // 8 MB
  unsigned short* hid = xb + (size_t)T_TOK * HDIM;                    // 25.4 MB
  int*   cnt  = (int*)(hid + (size_t)(HID_SHARED_BASE + T_TOK) * IDIM);
  int*   list = cnt + 16;
  float* wgt  = (float*)(list + EDIM * T_TOK);
  unsigned short* wT    = (unsigned short*)(wgt + EDIM * T_TOK);      // 54 MB
  unsigned short* gateT = wT;
  unsigned short* upT   = wT + (size_t)9 * 1048576;
  unsigned short* downT = wT + (size_t)18 * 1048576;
  unsigned short* R = wT + (size_t)27 * 1048576;                      // 25 MB
  size_t need = ((char*)(R + (size_t)T_TOK * 3 * HDIM)) - ws;
  const int useR = (ws_size >= need) ? 1 : 0;

  convert_x<<<(T_TOK * HDIM) / 1024, 256, 0, stream>>>(
      (const float4*)x, (ushort4*)xb, (float4*)out, cnt, useR ? 0 : 1);
  router2<<<T_TOK / 16, 256, 0, stream>>>(x, rw, cnt, list, wgt);

  SrcPtrs S; S.p[0] = sg; S.p[1] = su; S.p[2] = sd; S.p[3] = eg; S.p[4] = eu; S.p[5] = ed;
  transpose_all<<<dim3(8, 16, 27), 256, 0, stream>>>(S, wT);

  gateup9<<<dim3(IDIM / 64, T_TOK / 128, 9), 256, 0, stream>>>(xb, gateT, upT, hid, cnt, list);
  down9<<<dim3(HDIM / 128, T_TOK / 128, 9), 256, 0, stream>>>(hid, downT, out, R, useR,
                                                              cnt, list, wgt);
  if (useR) {
    combine_k<<<(T_TOK * HDIM / 8) / 256, 256, 0, stream>>>(
        (const float4*)x, R, (float4*)out);
  }
}